// Round 2
// baseline (14979.649 us; speedup 1.0000x reference)
//
#include <hip/hip_runtime.h>
#include <hip/hip_bf16.h>

#define NN 100000
#define EE 400000
#define ND 4096
#define DD 512
#define FF 8000
#define EMB 300
#define HID 600
#define NL 5
#define TCH 6272   // M-chunk rows for the MLP (98*64)

// Workspace budget (bytes, 256-aligned):
//   h        fp32 N*EMB      = 120.0 MB
//   ag       bf16 N*EMB      =  60.0 MB
//   t        fp32 TCH*HID    =  15.1 MB
//   ints (rowptr/cursor/col/deg/cnt/incl/...) ~ 5.7 MB
//   fragmean/outb/o0         ~ 20.7 MB
//   total                    ~ 221.4 MB

// ---------------- node feature init ----------------
static __global__ void k_init_h(const int* __restrict__ x, const float* __restrict__ ae1,
                                const float* __restrict__ ae2, float* __restrict__ h) {
    int idx = blockIdx.x * 256 + threadIdx.x;
    if (idx >= NN * EMB) return;
    int n = idx / EMB, c = idx - n * EMB;
    h[idx] = ae1[x[2 * n] * EMB + c] + ae2[x[2 * n + 1] * EMB + c];
}

// ---------------- degree + edge-attr histograms ----------------
static __global__ void k_count(const int* __restrict__ ei, const int* __restrict__ ea,
                               int* __restrict__ deg, int* __restrict__ cnt1, int* __restrict__ cnt2) {
    int e = blockIdx.x * 256 + threadIdx.x;
    if (e >= EE) return;
    int dst = ei[EE + e];
    atomicAdd(&deg[dst], 1);
    atomicAdd(&cnt1[dst * 3 + ea[2 * e]], 1);
    atomicAdd(&cnt2[dst * 3 + ea[2 * e + 1]], 1);
}

// ---------------- generic 3-pass exclusive scan ----------------
static __global__ void k_scan1(const int* __restrict__ in, int* __restrict__ incl,
                               int* __restrict__ bsum, int L) {
    __shared__ int s[256];
    int t = threadIdx.x, i = blockIdx.x * 256 + t;
    int v = (i < L) ? in[i] : 0;
    s[t] = v; __syncthreads();
    for (int o = 1; o < 256; o <<= 1) {
        int xv = (t >= o) ? s[t - o] : 0; __syncthreads();
        s[t] += xv; __syncthreads();
    }
    if (i < L) incl[i] = s[t];
    if (t == 255) bsum[blockIdx.x] = s[255];
}

static __global__ void k_scan2(const int* __restrict__ bsum, int* __restrict__ boff, int nb) {
    __shared__ int s[1024];
    int t = threadIdx.x;
    int v = (t < nb) ? bsum[t] : 0;
    s[t] = v; __syncthreads();
    for (int o = 1; o < 1024; o <<= 1) {
        int xv = (t >= o) ? s[t - o] : 0; __syncthreads();
        s[t] += xv; __syncthreads();
    }
    if (t < nb) boff[t] = s[t] - v;
}

static __global__ void k_scan3(const int* __restrict__ in, const int* __restrict__ incl,
                               const int* __restrict__ boff, int* __restrict__ op,
                               int* __restrict__ cursor, int L) {
    int i = blockIdx.x * 256 + threadIdx.x;
    if (i >= L) return;
    int ex = incl[i] - in[i] + boff[i / 256];
    op[i] = ex;
    if (cursor) cursor[i] = ex;
    if (i == L - 1) op[L] = ex + in[i];
}

// ---------------- CSR scatter (src ids grouped by dst) ----------------
static __global__ void k_scatter(const int* __restrict__ ei, int* __restrict__ cursor,
                                 int* __restrict__ col) {
    int e = blockIdx.x * 256 + threadIdx.x;
    if (e >= EE) return;
    int dst = ei[EE + e], src = ei[e];
    int p = atomicAdd(&cursor[dst], 1);
    col[p] = src;
}

// ---------------- GIN aggregation: aggr = sum_in h[src] + cnt@ee + h + selfbias ----
static __global__ void k_aggr(const float* __restrict__ h, __hip_bfloat16* __restrict__ out,
                              const int* __restrict__ rowptr, const int* __restrict__ col,
                              const int* __restrict__ cnt1, const int* __restrict__ cnt2,
                              const float* __restrict__ ge1l, const float* __restrict__ ge2l) {
    __shared__ float se[7 * EMB];  // ee1 rows0..2 | ee2 rows0..2 | self bias
    for (int idx = threadIdx.x; idx < 7 * EMB; idx += 256) {
        float v;
        if (idx < 3 * EMB) v = ge1l[idx];
        else if (idx < 6 * EMB) v = ge2l[idx - 3 * EMB];
        else { int c = idx - 6 * EMB; v = ge1l[4 * EMB + c] + ge2l[c]; }
        se[idx] = v;
    }
    __syncthreads();
    int w = threadIdx.x >> 6, lane = threadIdx.x & 63;
    int n = blockIdx.x * 4 + w;
    if (n >= NN) return;
    float c1a = (float)cnt1[n * 3], c1b = (float)cnt1[n * 3 + 1], c1c = (float)cnt1[n * 3 + 2];
    float c2a = (float)cnt2[n * 3], c2b = (float)cnt2[n * 3 + 1], c2c = (float)cnt2[n * 3 + 2];
    float acc[5];
    int cs[5];
#pragma unroll
    for (int j = 0; j < 5; j++) {
        int c = lane + 64 * j; cs[j] = c;
        if (c < EMB) {
            acc[j] = h[(size_t)n * EMB + c] + se[6 * EMB + c]
                   + c1a * se[c] + c1b * se[EMB + c] + c1c * se[2 * EMB + c]
                   + c2a * se[3 * EMB + c] + c2b * se[4 * EMB + c] + c2c * se[5 * EMB + c];
        } else acc[j] = 0.f;
    }
    int beg = rowptr[n], end = rowptr[n + 1];
    for (int p = beg; p < end; ++p) {
        int s = col[p];
        const float* hr = h + (size_t)s * EMB;
#pragma unroll
        for (int j = 0; j < 5; j++) if (cs[j] < EMB) acc[j] += hr[cs[j]];
    }
    __hip_bfloat16* orow = out + (size_t)n * EMB;
#pragma unroll
    for (int j = 0; j < 5; j++) if (cs[j] < EMB) orow[cs[j]] = __float2bfloat16(acc[j]);
}

// ---------------- SGEMM: C[M,Nc] = A[M,K] @ B[K,Nc] + bias (opt relu) ------
__device__ inline float ld_cvt(const float* p) { return *p; }
__device__ inline float ld_cvt(const __hip_bfloat16* p) { return __bfloat162float(*p); }

template <typename AT>
static __global__ __launch_bounds__(256) void k_gemm(
        const AT* __restrict__ A, const float* __restrict__ B,
        const float* __restrict__ bias, float* __restrict__ C,
        int M, int Nc, int K, int doRelu) {
    __shared__ float As[16][68];  // transposed A tile, padded (row stride 272B = 16B-aligned)
    __shared__ float Bs[16][64];
    int tid = threadIdx.x;
    int tx = tid & 15, ty = tid >> 4;
    int m0 = blockIdx.y * 64, n0 = blockIdx.x * 64;
    float acc[4][4] = {};
    for (int k0 = 0; k0 < K; k0 += 16) {
        {
            int k = tid & 15, mr = tid >> 4;
#pragma unroll
            for (int it = 0; it < 4; ++it) {
                int m = mr + 16 * it;
                float v = 0.f;
                if (m0 + m < M && k0 + k < K) v = ld_cvt(&A[(size_t)(m0 + m) * K + k0 + k]);
                As[k][m] = v;
            }
        }
        {
            int nn2 = tid & 63, kr = tid >> 6;
#pragma unroll
            for (int it = 0; it < 4; ++it) {
                int k = kr + 4 * it;
                float v = 0.f;
                if (k0 + k < K && n0 + nn2 < Nc) v = B[(size_t)(k0 + k) * Nc + n0 + nn2];
                Bs[k][nn2] = v;
            }
        }
        __syncthreads();
#pragma unroll
        for (int kk = 0; kk < 16; ++kk) {
            float4 a4 = *(const float4*)&As[kk][ty * 4];
            float4 b4 = *(const float4*)&Bs[kk][tx * 4];
            float av[4] = {a4.x, a4.y, a4.z, a4.w};
            float bv[4] = {b4.x, b4.y, b4.z, b4.w};
#pragma unroll
            for (int i = 0; i < 4; i++)
#pragma unroll
                for (int j = 0; j < 4; j++)
                    acc[i][j] += av[i] * bv[j];
        }
        __syncthreads();
    }
#pragma unroll
    for (int i = 0; i < 4; i++) {
        int m = m0 + ty * 4 + i;
        if (m >= M) continue;
#pragma unroll
        for (int j = 0; j < 4; j++) {
            int nn2 = n0 + tx * 4 + j;
            if (nn2 >= Nc) continue;
            float v = acc[i][j] + bias[nn2];
            if (doRelu) v = fmaxf(v, 0.f);
            C[(size_t)m * Nc + nn2] = v;
        }
    }
}

// ---------------- batchnorm: column sums / normalize ----------------
static __global__ void k_bnstats(const float* __restrict__ h, float* __restrict__ colsum,
                                 float* __restrict__ colsq) {
    int t = threadIdx.x;
    int r0 = blockIdx.x * 256;
    int rend = min(r0 + 256, NN);
    float s0 = 0, q0 = 0, s1 = 0, q1 = 0;
    int c1 = t;
    int c2 = t + 256;
    for (int r = r0; r < rend; ++r) {
        const float* row = h + (size_t)r * EMB;
        float v = row[c1]; s0 += v; q0 += v * v;
        if (c2 < EMB) { float u = row[c2]; s1 += u; q1 += u * u; }
    }
    atomicAdd(&colsum[c1], s0); atomicAdd(&colsq[c1], q0);
    if (c2 < EMB) { atomicAdd(&colsum[c2], s1); atomicAdd(&colsq[c2], q1); }
}

static __global__ void k_bnfinal(const float* __restrict__ colsum, const float* __restrict__ colsq,
                                 const float* __restrict__ g, const float* __restrict__ b,
                                 float* __restrict__ scv) {
    int c = threadIdx.x;
    if (c >= EMB) return;
    float mean = colsum[c] * (1.f / NN);
    float var = colsq[c] * (1.f / NN) - mean * mean;
    float rs = rsqrtf(var + 1e-5f);
    float sc = rs * g[c];
    scv[c] = sc;
    scv[EMB + c] = b[c] - mean * sc;
}

static __global__ void k_bnapply(float* __restrict__ h, const float* __restrict__ scv, int doRelu) {
    int idx = blockIdx.x * 256 + threadIdx.x;
    if (idx >= NN * EMB) return;
    int c = idx % EMB;
    float v = h[idx] * scv[c] + scv[EMB + c];
    if (doRelu) v = fmaxf(v, 0.f);
    h[idx] = v;
}

// ---------------- fragment pooling ----------------
static __global__ void k_fragcnt(const int* __restrict__ fb, int* __restrict__ fcnt) {
    int i = blockIdx.x * 256 + threadIdx.x;
    if (i >= NN) return;
    atomicAdd(&fcnt[fb[i]], 1);
}

static __global__ void k_fragmean(const float* __restrict__ h, const int* __restrict__ fstart,
                                  float* __restrict__ fm) {
    int w = threadIdx.x >> 6, lane = threadIdx.x & 63;
    int f = blockIdx.x * 4 + w;
    if (f >= FF) return;
    int beg = fstart[f], end = fstart[f + 1];
    float inv = (end > beg) ? 1.f / (float)(end - beg) : 0.f;
    float acc[5]; int cs[5];
#pragma unroll
    for (int j = 0; j < 5; j++) { cs[j] = lane + 64 * j; acc[j] = 0.f; }
    for (int r = beg; r < end; ++r) {
        const float* row = h + (size_t)r * EMB;
#pragma unroll
        for (int j = 0; j < 5; j++) if (cs[j] < EMB) acc[j] += row[cs[j]];
    }
#pragma unroll
    for (int j = 0; j < 5; j++) if (cs[j] < EMB) fm[(size_t)f * EMB + cs[j]] = acc[j] * inv;
}

// ---------------- head: out, out0, logits ----------------
static __global__ void k_build_out(const float* __restrict__ h, const float* __restrict__ fm,
                                   const int* __restrict__ didx, const int* __restrict__ fb,
                                   float* __restrict__ outb) {
    int idx = blockIdx.x * 256 + threadIdx.x;
    if (idx >= ND * HID) return;
    int d = idx / HID, c = idx - d * HID;
    int n = didx[d];
    float v = (c < EMB) ? h[(size_t)n * EMB + c] : fm[(size_t)fb[n] * EMB + (c - EMB)];
    outb[idx] = v * (1.f / EMB);
}

static __global__ void k_out0(const float* __restrict__ outb, const int* __restrict__ dei,
                              const int* __restrict__ dea, const float* __restrict__ E1,
                              const float* __restrict__ E2, float* __restrict__ o0) {
    __shared__ float v[HID];
    int d = blockIdx.x, tid = threadIdx.x;
    int r = dei[d];
    for (int c = tid; c < HID; c += 256) v[c] = outb[(size_t)r * HID + c];
    __syncthreads();
    const float* p1 = E1 + (size_t)dea[2 * d] * HID * HID;
    const float* p2 = E2 + (size_t)dea[2 * d + 1] * HID * HID;
    for (int m = tid; m < HID; m += 256) {
        float acc = 0.f;
#pragma unroll 4
        for (int k = 0; k < HID; ++k)
            acc += v[k] * (p1[(size_t)k * HID + m] + p2[(size_t)k * HID + m]);
        o0[(size_t)d * HID + m] = acc;
    }
}

static __global__ void k_logits(const float* __restrict__ o0, const float* __restrict__ outb,
                                const int* __restrict__ dei, float* __restrict__ dout) {
    int d = blockIdx.x;
    int tid = threadIdx.x, lane = tid & 63;
    int which = tid >> 6;  // 0: logits[d], 1: logits[DD+d] (rolled)
    int dsel = which ? (d + DD - 1) % DD : d;
    const float* a = o0 + (size_t)d * HID;
    const float* bv = outb + (size_t)dei[DD + dsel] * HID;
    float s = 0.f;
    for (int c = lane; c < HID; c += 64) s += a[c] * bv[c];
    for (int o = 32; o > 0; o >>= 1) s += __shfl_down(s, o);
    if (lane == 0) dout[which ? DD + d : d] = s;
}

extern "C" void kernel_launch(void* const* d_in, const int* in_sizes, int n_in,
                              void* d_out, int out_size, void* d_ws, size_t ws_size,
                              hipStream_t stream) {
    const int* x    = (const int*)d_in[0];
    const int* ei   = (const int*)d_in[1];
    const int* ea   = (const int*)d_in[2];
    const int* didx = (const int*)d_in[3];
    const int* fb   = (const int*)d_in[4];
    const int* dei  = (const int*)d_in[5];
    const int* dea  = (const int*)d_in[6];
    const float* ae1 = (const float*)d_in[7];
    const float* ae2 = (const float*)d_in[8];
    const float* ge1 = (const float*)d_in[9];
    const float* ge2 = (const float*)d_in[10];
    const float* W1  = (const float*)d_in[11];
    const float* b1  = (const float*)d_in[12];
    const float* W2  = (const float*)d_in[13];
    const float* b2  = (const float*)d_in[14];
    const float* bng = (const float*)d_in[15];
    const float* bnb = (const float*)d_in[16];
    const float* E1  = (const float*)d_in[17];
    const float* E2  = (const float*)d_in[18];
    float* dout = (float*)d_out;

    char* w = (char*)d_ws;
    auto alloc = [&](size_t bytes) -> void* {
        void* p = (void*)w;
        w += (bytes + 255) & ~(size_t)255;
        return p;
    };
    float* h      = (float*)alloc((size_t)NN * EMB * 4);          // 120.0 MB
    __hip_bfloat16* ag = (__hip_bfloat16*)alloc((size_t)NN * EMB * 2);  // 60.0 MB
    float* t      = (float*)alloc((size_t)TCH * HID * 4);         // 15.1 MB
    int* rowptr   = (int*)alloc((size_t)(NN + 1) * 4);
    int* cursor   = (int*)alloc((size_t)NN * 4);
    int* col      = (int*)alloc((size_t)EE * 4);
    int* deg      = (int*)alloc((size_t)NN * 4);
    int* cnt1     = (int*)alloc((size_t)NN * 3 * 4);
    int* cnt2     = (int*)alloc((size_t)NN * 3 * 4);
    int* incl     = (int*)alloc((size_t)NN * 4);
    int* bsum     = (int*)alloc(4096);
    int* boff     = (int*)alloc(4096);
    int* fcnt     = (int*)alloc((size_t)FF * 4);
    int* fstart   = (int*)alloc((size_t)(FF + 1) * 4);
    float* colsum = (float*)alloc(2 * EMB * 4);
    float* colsq  = colsum + EMB;
    float* scv    = (float*)alloc(2 * EMB * 4);
    float* fragmean = (float*)alloc((size_t)FF * EMB * 4);        // 9.6 MB
    float* outb   = (float*)alloc((size_t)ND * HID * 4);          // 9.8 MB
    float* o0     = (float*)alloc((size_t)DD * HID * 4);          // 1.2 MB
    // total ~ 221.4 MB

    hipMemsetAsync(deg, 0, (size_t)NN * 4, stream);
    hipMemsetAsync(cnt1, 0, (size_t)NN * 3 * 4, stream);
    hipMemsetAsync(cnt2, 0, (size_t)NN * 3 * 4, stream);
    hipMemsetAsync(fcnt, 0, (size_t)FF * 4, stream);

    k_init_h<<<(NN * EMB + 255) / 256, 256, 0, stream>>>(x, ae1, ae2, h);
    k_count<<<(EE + 255) / 256, 256, 0, stream>>>(ei, ea, deg, cnt1, cnt2);

    int nb = (NN + 255) / 256;
    k_scan1<<<nb, 256, 0, stream>>>(deg, incl, bsum, NN);
    k_scan2<<<1, 1024, 0, stream>>>(bsum, boff, nb);
    k_scan3<<<nb, 256, 0, stream>>>(deg, incl, boff, rowptr, cursor, NN);
    k_scatter<<<(EE + 255) / 256, 256, 0, stream>>>(ei, cursor, col);

    k_fragcnt<<<nb, 256, 0, stream>>>(fb, fcnt);
    int nbf = (FF + 255) / 256;
    k_scan1<<<nbf, 256, 0, stream>>>(fcnt, incl, bsum, FF);
    k_scan2<<<1, 1024, 0, stream>>>(bsum, boff, nbf);
    k_scan3<<<nbf, 256, 0, stream>>>(fcnt, incl, boff, fstart, (int*)nullptr, FF);

    for (int l = 0; l < NL; l++) {
        const float* ge1l = ge1 + (size_t)l * 6 * EMB;
        const float* ge2l = ge2 + (size_t)l * 3 * EMB;
        k_aggr<<<(NN + 3) / 4, 256, 0, stream>>>(h, ag, rowptr, col, cnt1, cnt2, ge1l, ge2l);
        for (int c0 = 0; c0 < NN; c0 += TCH) {
            int Mc = (NN - c0 < TCH) ? (NN - c0) : TCH;
            dim3 g1((HID + 63) / 64, (Mc + 63) / 64);
            k_gemm<__hip_bfloat16><<<g1, 256, 0, stream>>>(ag + (size_t)c0 * EMB,
                                           W1 + (size_t)l * EMB * HID,
                                           b1 + (size_t)l * HID, t, Mc, HID, EMB, 1);
            dim3 g2((EMB + 63) / 64, (Mc + 63) / 64);
            k_gemm<float><<<g2, 256, 0, stream>>>(t, W2 + (size_t)l * HID * EMB,
                                           b2 + (size_t)l * EMB, h + (size_t)c0 * EMB, Mc, EMB, HID, 0);
        }
        hipMemsetAsync(colsum, 0, 2 * EMB * 4, stream);
        k_bnstats<<<nb, 256, 0, stream>>>(h, colsum, colsq);
        k_bnfinal<<<1, 320, 0, stream>>>(colsum, colsq, bng + (size_t)l * EMB, bnb + (size_t)l * EMB, scv);
        k_bnapply<<<(NN * EMB + 255) / 256, 256, 0, stream>>>(h, scv, (l < NL - 1) ? 1 : 0);
    }

    k_fragmean<<<(FF + 3) / 4, 256, 0, stream>>>(h, fstart, fragmean);
    k_build_out<<<(ND * HID + 255) / 256, 256, 0, stream>>>(h, fragmean, didx, fb, outb);
    k_out0<<<DD, 256, 0, stream>>>(outb, dei, dea, E1, E2, o0);
    k_logits<<<DD, 128, 0, stream>>>(o0, outb, dei, dout);
}

// Round 3
// 4475.574 us; speedup vs baseline: 3.3470x; 3.3470x over previous
//
#include <hip/hip_runtime.h>
#include <hip/hip_bf16.h>
#include <stdint.h>

#define NN 100000
#define EE 400000
#define ND 4096
#define DD 512
#define FF 8000
#define EMB 300
#define HID 600
#define NL 5
#define TCH 12544     // M-chunk rows (98*128)
#define MPAD 100096   // 782*128: ag plane rows (padded so M-tiles never read OOB)

typedef unsigned short u16;
typedef __bf16 bf16x8 __attribute__((ext_vector_type(8)));
typedef float f32x4 __attribute__((ext_vector_type(4)));

static __device__ inline u16 f2bf(float v) {
    union { __hip_bfloat16 b; u16 u; } c; c.b = __float2bfloat16(v); return c.u;
}
static __device__ inline float bf2f(u16 u) {
    union { u16 u; __hip_bfloat16 b; } c; c.u = u; return __bfloat162float(c.b);
}

// ---------------- node feature init ----------------
static __global__ void k_init_h(const int* __restrict__ x, const float* __restrict__ ae1,
                                const float* __restrict__ ae2, float* __restrict__ h) {
    int idx = blockIdx.x * 256 + threadIdx.x;
    if (idx >= NN * EMB) return;
    int n = idx / EMB, c = idx - n * EMB;
    h[idx] = ae1[x[2 * n] * EMB + c] + ae2[x[2 * n + 1] * EMB + c];
}

// ---------------- degree + edge-attr histograms ----------------
static __global__ void k_count(const int* __restrict__ ei, const int* __restrict__ ea,
                               int* __restrict__ deg, int* __restrict__ cnt1, int* __restrict__ cnt2) {
    int e = blockIdx.x * 256 + threadIdx.x;
    if (e >= EE) return;
    int dst = ei[EE + e];
    atomicAdd(&deg[dst], 1);
    atomicAdd(&cnt1[dst * 3 + ea[2 * e]], 1);
    atomicAdd(&cnt2[dst * 3 + ea[2 * e + 1]], 1);
}

// ---------------- generic 3-pass exclusive scan ----------------
static __global__ void k_scan1(const int* __restrict__ in, int* __restrict__ incl,
                               int* __restrict__ bsum, int L) {
    __shared__ int s[256];
    int t = threadIdx.x, i = blockIdx.x * 256 + t;
    int v = (i < L) ? in[i] : 0;
    s[t] = v; __syncthreads();
    for (int o = 1; o < 256; o <<= 1) {
        int xv = (t >= o) ? s[t - o] : 0; __syncthreads();
        s[t] += xv; __syncthreads();
    }
    if (i < L) incl[i] = s[t];
    if (t == 255) bsum[blockIdx.x] = s[255];
}

static __global__ void k_scan2(const int* __restrict__ bsum, int* __restrict__ boff, int nb) {
    __shared__ int s[1024];
    int t = threadIdx.x;
    int v = (t < nb) ? bsum[t] : 0;
    s[t] = v; __syncthreads();
    for (int o = 1; o < 1024; o <<= 1) {
        int xv = (t >= o) ? s[t - o] : 0; __syncthreads();
        s[t] += xv; __syncthreads();
    }
    if (t < nb) boff[t] = s[t] - v;
}

static __global__ void k_scan3(const int* __restrict__ in, const int* __restrict__ incl,
                               const int* __restrict__ boff, int* __restrict__ op,
                               int* __restrict__ cursor, int L) {
    int i = blockIdx.x * 256 + threadIdx.x;
    if (i >= L) return;
    int ex = incl[i] - in[i] + boff[i / 256];
    op[i] = ex;
    if (cursor) cursor[i] = ex;
    if (i == L - 1) op[L] = ex + in[i];
}

// ---------------- CSR scatter (src ids grouped by dst) ----------------
static __global__ void k_scatter(const int* __restrict__ ei, int* __restrict__ cursor,
                                 int* __restrict__ col) {
    int e = blockIdx.x * 256 + threadIdx.x;
    if (e >= EE) return;
    int dst = ei[EE + e], src = ei[e];
    int p = atomicAdd(&cursor[dst], 1);
    col[p] = src;
}

// ---------------- GIN aggregation -> bf16 plane [MPAD,320] ----------------
static __global__ void k_aggr(const float* __restrict__ h, u16* __restrict__ out,
                              const int* __restrict__ rowptr, const int* __restrict__ col,
                              const int* __restrict__ cnt1, const int* __restrict__ cnt2,
                              const float* __restrict__ ge1l, const float* __restrict__ ge2l) {
    __shared__ float se[7 * EMB];
    for (int idx = threadIdx.x; idx < 7 * EMB; idx += 256) {
        float v;
        if (idx < 3 * EMB) v = ge1l[idx];
        else if (idx < 6 * EMB) v = ge2l[idx - 3 * EMB];
        else { int c = idx - 6 * EMB; v = ge1l[4 * EMB + c] + ge2l[c]; }
        se[idx] = v;
    }
    __syncthreads();
    int w = threadIdx.x >> 6, lane = threadIdx.x & 63;
    int n = blockIdx.x * 4 + w;
    if (n >= NN) return;
    float c1a = (float)cnt1[n * 3], c1b = (float)cnt1[n * 3 + 1], c1c = (float)cnt1[n * 3 + 2];
    float c2a = (float)cnt2[n * 3], c2b = (float)cnt2[n * 3 + 1], c2c = (float)cnt2[n * 3 + 2];
    float acc[5];
    int cs[5];
#pragma unroll
    for (int j = 0; j < 5; j++) {
        int c = lane + 64 * j; cs[j] = c;
        if (c < EMB) {
            acc[j] = h[(size_t)n * EMB + c] + se[6 * EMB + c]
                   + c1a * se[c] + c1b * se[EMB + c] + c1c * se[2 * EMB + c]
                   + c2a * se[3 * EMB + c] + c2b * se[4 * EMB + c] + c2c * se[5 * EMB + c];
        } else acc[j] = 0.f;
    }
    int beg = rowptr[n], end = rowptr[n + 1];
    for (int p = beg; p < end; ++p) {
        int s = col[p];
        const float* hr = h + (size_t)s * EMB;
#pragma unroll
        for (int j = 0; j < 5; j++) if (cs[j] < EMB) acc[j] += hr[cs[j]];
    }
    u16* orow = out + (size_t)n * 320;
#pragma unroll
    for (int j = 0; j < 5; j++) orow[cs[j]] = (cs[j] < EMB) ? f2bf(acc[j]) : (u16)0;
}

// ---------------- weight packing: transposed, padded, hi/lo split ------------
// W1p [NL][640 n][640 k2]: k2<320 -> hi(W1[k2][n]); k2>=320 -> lo(W1[k2-320][n])
static __global__ void k_packW1(const float* __restrict__ W1, u16* __restrict__ W1p) {
    int idx = blockIdx.x * 256 + threadIdx.x;
    const int per = 640 * 640;
    if (idx >= NL * per) return;
    int l = idx / per, rem = idx % per;
    int n = rem / 640, k2 = rem % 640;
    int k = (k2 < 320) ? k2 : (k2 - 320);
    float v = (k < EMB && n < HID) ? W1[(size_t)l * EMB * HID + (size_t)k * HID + n] : 0.f;
    u16 hi = f2bf(v);
    W1p[idx] = (k2 < 320) ? hi : f2bf(v - bf2f(hi));
}

// W2p [NL][384 n][1920 k3]: seg0=hi, seg1=lo, seg2=hi (pairs A3=[th;th;tl])
static __global__ void k_packW2(const float* __restrict__ W2, u16* __restrict__ W2p) {
    int idx = blockIdx.x * 256 + threadIdx.x;
    const int per = 384 * 1920;
    if (idx >= NL * per) return;
    int l = idx / per, rem = idx % per;
    int n = rem / 1920, k3 = rem % 1920;
    int seg = k3 / 640, k = k3 % 640;
    float v = (k < HID && n < EMB) ? W2[(size_t)l * HID * EMB + (size_t)k * EMB + n] : 0.f;
    u16 hi = f2bf(v);
    W2p[idx] = (seg == 1) ? f2bf(v - bf2f(hi)) : hi;
}

static __global__ void k_packb(const float* __restrict__ b1, const float* __restrict__ b2,
                               float* __restrict__ b1p, float* __restrict__ b2p) {
    int idx = blockIdx.x * 256 + threadIdx.x;
    if (idx < NL * 640) {
        int l = idx / 640, n = idx % 640;
        b1p[idx] = (n < HID) ? b1[l * HID + n] : 0.f;
    } else if (idx < NL * 640 + NL * 384) {
        int j = idx - NL * 640;
        int l = j / 384, n = j % 384;
        b2p[j] = (n < EMB) ? b2[l * EMB + n] : 0.f;
    }
}

// ---------------- MFMA GEMM -----------------------------------------------
// MODE 1: C=relu(ag@[W1h;W1l]+b1) -> split store th/tl. BM=128, K2=640, A stride 320.
// MODE 2: h=[th;th;tl]@[W2h;W2l;W2h]+b2 (fp32).       BM=64,  K3=1920, A stride 640.
template <int MODE>
static __global__ __launch_bounds__(256) void k_mfma(
        const u16* __restrict__ A0, const u16* __restrict__ A1,
        const u16* __restrict__ Bp, const float* __restrict__ bias,
        u16* __restrict__ Th, u16* __restrict__ Tl,
        float* __restrict__ Cf, int Mc) {
    constexpr int BM    = (MODE == 1) ? 128 : 64;
    constexpr int STRA  = (MODE == 1) ? 320 : 640;
    constexpr int STRB  = (MODE == 1) ? 640 : 1920;
    constexpr int NSTEP = (MODE == 1) ? 20 : 60;
    constexpr int MF    = 4;
    constexpr int NF    = (MODE == 1) ? 4 : 2;

    __shared__ __align__(16) u16 sA[BM * 32];
    __shared__ __align__(16) u16 sB[128 * 32];

    int tid = threadIdx.x;
    int lane = tid & 63, wv = tid >> 6;
    int wm = (MODE == 1) ? (wv >> 1) : 0;
    int wn = (MODE == 1) ? (wv & 1) : wv;
    int m0 = blockIdx.y * BM;
    int n0 = blockIdx.x * 128;

    int sr = tid >> 2, scb = tid & 3;   // staging: row 0..63, 16B col-block 0..3

    // XOR swizzle: 16B block cb of row stored at cb ^ ((row>>1)&3) -> frag reads 2-way (free)
#define LOFF(row, cb) ((row) * 32 + (((cb) ^ (((row) >> 1) & 3)) * 8))

    uint4 rA0, rA1, rB0, rB1;
    auto do_load = [&](int ks) {
        int kk = ks * 32;
        const u16* ap; int kc;
        if (MODE == 1) { ap = A0; kc = (kk < 320) ? kk : kk - 320; }
        else {
            ap = (kk < 1280) ? A0 : A1;
            kc = (kk < 640) ? kk : ((kk < 1280) ? kk - 640 : kk - 1280);
        }
        const u16* as = ap + (size_t)(m0 + sr) * STRA + kc + scb * 8;
        rA0 = *(const uint4*)as;
        if (MODE == 1) rA1 = *(const uint4*)(as + (size_t)64 * STRA);
        const u16* bs = Bp + (size_t)(n0 + sr) * STRB + kk + scb * 8;
        rB0 = *(const uint4*)bs;
        rB1 = *(const uint4*)(bs + (size_t)64 * STRB);
    };

    do_load(0);
    f32x4 acc[MF][NF];
#pragma unroll
    for (int i = 0; i < MF; i++)
#pragma unroll
        for (int j = 0; j < NF; j++) {
            acc[i][j][0] = 0.f; acc[i][j][1] = 0.f; acc[i][j][2] = 0.f; acc[i][j][3] = 0.f;
        }

    int lrow = lane & 15, lcb = lane >> 4;
    for (int ks = 0; ks < NSTEP; ++ks) {
        __syncthreads();
        *(uint4*)&sA[LOFF(sr, scb)] = rA0;
        if (MODE == 1) *(uint4*)&sA[LOFF(sr + 64, scb)] = rA1;
        *(uint4*)&sB[LOFF(sr, scb)] = rB0;
        *(uint4*)&sB[LOFF(sr + 64, scb)] = rB1;
        __syncthreads();
        if (ks + 1 < NSTEP) do_load(ks + 1);
        bf16x8 af[MF], bfr[NF];
#pragma unroll
        for (int mf = 0; mf < MF; ++mf) {
            int r = wm * 64 + mf * 16 + lrow;
            af[mf] = *(const bf16x8*)&sA[LOFF(r, lcb)];
        }
#pragma unroll
        for (int nf = 0; nf < NF; ++nf) {
            int r = wn * (NF * 16) + nf * 16 + lrow;
            bfr[nf] = *(const bf16x8*)&sB[LOFF(r, lcb)];
        }
#pragma unroll
        for (int mf = 0; mf < MF; ++mf)
#pragma unroll
            for (int nf = 0; nf < NF; ++nf)
                acc[mf][nf] = __builtin_amdgcn_mfma_f32_16x16x32_bf16(af[mf], bfr[nf], acc[mf][nf], 0, 0, 0);
    }
#undef LOFF

    // epilogue: C/D layout col=lane&15, row=(lane>>4)*4+reg  [m89-verified]
    int lrow4 = (lane >> 4) * 4, lcol = lane & 15;
#pragma unroll
    for (int mf = 0; mf < MF; ++mf) {
#pragma unroll
        for (int nf = 0; nf < NF; ++nf) {
            int colg = n0 + wn * (NF * 16) + nf * 16 + lcol;
#pragma unroll
            for (int rg = 0; rg < 4; ++rg) {
                int rowl = m0 + wm * 64 + mf * 16 + lrow4 + rg;
                float v = acc[mf][nf][rg] + bias[colg];
                if (MODE == 1) {
                    v = fmaxf(v, 0.f);
                    u16 hi = f2bf(v);
                    Th[(size_t)rowl * 640 + colg] = hi;
                    Tl[(size_t)rowl * 640 + colg] = f2bf(v - bf2f(hi));
                } else {
                    if (rowl < Mc && colg < EMB)
                        Cf[(size_t)rowl * EMB + colg] = v;
                }
            }
        }
    }
}

// ---------------- batchnorm ----------------
static __global__ void k_bnstats(const float* __restrict__ h, float* __restrict__ colsum,
                                 float* __restrict__ colsq) {
    int t = threadIdx.x;
    int r0 = blockIdx.x * 256;
    int rend = min(r0 + 256, NN);
    float s0 = 0, q0 = 0, s1 = 0, q1 = 0;
    int c1 = t;
    int c2 = t + 256;
    for (int r = r0; r < rend; ++r) {
        const float* row = h + (size_t)r * EMB;
        float v = row[c1]; s0 += v; q0 += v * v;
        if (c2 < EMB) { float u = row[c2]; s1 += u; q1 += u * u; }
    }
    atomicAdd(&colsum[c1], s0); atomicAdd(&colsq[c1], q0);
    if (c2 < EMB) { atomicAdd(&colsum[c2], s1); atomicAdd(&colsq[c2], q1); }
}

static __global__ void k_bnfinal(const float* __restrict__ colsum, const float* __restrict__ colsq,
                                 const float* __restrict__ g, const float* __restrict__ b,
                                 float* __restrict__ scv) {
    int c = threadIdx.x;
    if (c >= EMB) return;
    float mean = colsum[c] * (1.f / NN);
    float var = colsq[c] * (1.f / NN) - mean * mean;
    float rs = rsqrtf(var + 1e-5f);
    float sc = rs * g[c];
    scv[c] = sc;
    scv[EMB + c] = b[c] - mean * sc;
}

static __global__ void k_bnapply(float* __restrict__ h, const float* __restrict__ scv, int doRelu) {
    int idx = blockIdx.x * 256 + threadIdx.x;
    if (idx >= NN * EMB) return;
    int c = idx % EMB;
    float v = h[idx] * scv[c] + scv[EMB + c];
    if (doRelu) v = fmaxf(v, 0.f);
    h[idx] = v;
}

// ---------------- fragment pooling ----------------
static __global__ void k_fragcnt(const int* __restrict__ fb, int* __restrict__ fcnt) {
    int i = blockIdx.x * 256 + threadIdx.x;
    if (i >= NN) return;
    atomicAdd(&fcnt[fb[i]], 1);
}

static __global__ void k_fragmean(const float* __restrict__ h, const int* __restrict__ fstart,
                                  float* __restrict__ fm) {
    int w = threadIdx.x >> 6, lane = threadIdx.x & 63;
    int f = blockIdx.x * 4 + w;
    if (f >= FF) return;
    int beg = fstart[f], end = fstart[f + 1];
    float inv = (end > beg) ? 1.f / (float)(end - beg) : 0.f;
    float acc[5]; int cs[5];
#pragma unroll
    for (int j = 0; j < 5; j++) { cs[j] = lane + 64 * j; acc[j] = 0.f; }
    for (int r = beg; r < end; ++r) {
        const float* row = h + (size_t)r * EMB;
#pragma unroll
        for (int j = 0; j < 5; j++) if (cs[j] < EMB) acc[j] += row[cs[j]];
    }
#pragma unroll
    for (int j = 0; j < 5; j++) if (cs[j] < EMB) fm[(size_t)f * EMB + cs[j]] = acc[j] * inv;
}

// ---------------- head ----------------
static __global__ void k_build_out(const float* __restrict__ h, const float* __restrict__ fm,
                                   const int* __restrict__ didx, const int* __restrict__ fb,
                                   float* __restrict__ outb) {
    int idx = blockIdx.x * 256 + threadIdx.x;
    if (idx >= ND * HID) return;
    int d = idx / HID, c = idx - d * HID;
    int n = didx[d];
    float v = (c < EMB) ? h[(size_t)n * EMB + c] : fm[(size_t)fb[n] * EMB + (c - EMB)];
    outb[idx] = v * (1.f / EMB);
}

static __global__ void k_out0(const float* __restrict__ outb, const int* __restrict__ dei,
                              const int* __restrict__ dea, const float* __restrict__ E1,
                              const float* __restrict__ E2, float* __restrict__ o0) {
    __shared__ float v[HID];
    int d = blockIdx.x, tid = threadIdx.x;
    int r = dei[d];
    for (int c = tid; c < HID; c += 256) v[c] = outb[(size_t)r * HID + c];
    __syncthreads();
    const float* p1 = E1 + (size_t)dea[2 * d] * HID * HID;
    const float* p2 = E2 + (size_t)dea[2 * d + 1] * HID * HID;
    for (int m = tid; m < HID; m += 256) {
        float acc = 0.f;
#pragma unroll 4
        for (int k = 0; k < HID; ++k)
            acc += v[k] * (p1[(size_t)k * HID + m] + p2[(size_t)k * HID + m]);
        o0[(size_t)d * HID + m] = acc;
    }
}

static __global__ void k_logits(const float* __restrict__ o0, const float* __restrict__ outb,
                                const int* __restrict__ dei, float* __restrict__ dout) {
    int d = blockIdx.x;
    int tid = threadIdx.x, lane = tid & 63;
    int which = tid >> 6;
    int dsel = which ? (d + DD - 1) % DD : d;
    const float* a = o0 + (size_t)d * HID;
    const float* bv = outb + (size_t)dei[DD + dsel] * HID;
    float s = 0.f;
    for (int c = lane; c < HID; c += 64) s += a[c] * bv[c];
    for (int o = 32; o > 0; o >>= 1) s += __shfl_down(s, o);
    if (lane == 0) dout[which ? DD + d : d] = s;
}

extern "C" void kernel_launch(void* const* d_in, const int* in_sizes, int n_in,
                              void* d_out, int out_size, void* d_ws, size_t ws_size,
                              hipStream_t stream) {
    const int* x    = (const int*)d_in[0];
    const int* ei   = (const int*)d_in[1];
    const int* ea   = (const int*)d_in[2];
    const int* didx = (const int*)d_in[3];
    const int* fb   = (const int*)d_in[4];
    const int* dei  = (const int*)d_in[5];
    const int* dea  = (const int*)d_in[6];
    const float* ae1 = (const float*)d_in[7];
    const float* ae2 = (const float*)d_in[8];
    const float* ge1 = (const float*)d_in[9];
    const float* ge2 = (const float*)d_in[10];
    const float* W1  = (const float*)d_in[11];
    const float* b1  = (const float*)d_in[12];
    const float* W2  = (const float*)d_in[13];
    const float* b2  = (const float*)d_in[14];
    const float* bng = (const float*)d_in[15];
    const float* bnb = (const float*)d_in[16];
    const float* E1  = (const float*)d_in[17];
    const float* E2  = (const float*)d_in[18];
    float* dout = (float*)d_out;

    char* w = (char*)d_ws;
    auto alloc = [&](size_t bytes) -> void* {
        void* p = (void*)w;
        w += (bytes + 255) & ~(size_t)255;
        return p;
    };
    float* h    = (float*)alloc((size_t)NN * EMB * 4);        // 120.0 MB
    u16* ag     = (u16*)alloc((size_t)MPAD * 320 * 2);        //  64.1 MB
    u16* th     = (u16*)alloc((size_t)TCH * 640 * 2);         //  16.1 MB
    u16* tl     = (u16*)alloc((size_t)TCH * 640 * 2);         //  16.1 MB
    u16* W1p    = (u16*)alloc((size_t)NL * 640 * 640 * 2);    //   4.1 MB
    u16* W2p    = (u16*)alloc((size_t)NL * 384 * 1920 * 2);   //   7.4 MB
    float* b1p  = (float*)alloc((size_t)NL * 640 * 4);
    float* b2p  = (float*)alloc((size_t)NL * 384 * 4);
    int* rowptr = (int*)alloc((size_t)(NN + 1) * 4);
    int* cursor = (int*)alloc((size_t)NN * 4);
    int* col    = (int*)alloc((size_t)EE * 4);
    int* deg    = (int*)alloc((size_t)NN * 4);
    int* cnt1   = (int*)alloc((size_t)NN * 3 * 4);
    int* cnt2   = (int*)alloc((size_t)NN * 3 * 4);
    int* incl   = (int*)alloc((size_t)NN * 4);
    int* bsum   = (int*)alloc(4096);
    int* boff   = (int*)alloc(4096);
    int* fcnt   = (int*)alloc((size_t)FF * 4);
    int* fstart = (int*)alloc((size_t)(FF + 1) * 4);
    float* colsum = (float*)alloc(2 * EMB * 4);
    float* colsq  = colsum + EMB;
    float* scv    = (float*)alloc(2 * EMB * 4);
    // tail buffers overlay th/tl (dead after last GEMM2): 20.7 MB < 32.1 MB
    float* fragmean = (float*)th;
    float* outb     = fragmean + (size_t)FF * EMB;
    float* o0       = outb + (size_t)ND * HID;
    // total ~233 MB

    hipMemsetAsync(deg, 0, (size_t)NN * 4, stream);
    hipMemsetAsync(cnt1, 0, (size_t)NN * 3 * 4, stream);
    hipMemsetAsync(cnt2, 0, (size_t)NN * 3 * 4, stream);
    hipMemsetAsync(fcnt, 0, (size_t)FF * 4, stream);

    k_packW1<<<(NL * 640 * 640 + 255) / 256, 256, 0, stream>>>(W1, W1p);
    k_packW2<<<(NL * 384 * 1920 + 255) / 256, 256, 0, stream>>>(W2, W2p);
    k_packb<<<(NL * (640 + 384) + 255) / 256, 256, 0, stream>>>(b1, b2, b1p, b2p);

    k_init_h<<<(NN * EMB + 255) / 256, 256, 0, stream>>>(x, ae1, ae2, h);
    k_count<<<(EE + 255) / 256, 256, 0, stream>>>(ei, ea, deg, cnt1, cnt2);

    int nb = (NN + 255) / 256;
    k_scan1<<<nb, 256, 0, stream>>>(deg, incl, bsum, NN);
    k_scan2<<<1, 1024, 0, stream>>>(bsum, boff, nb);
    k_scan3<<<nb, 256, 0, stream>>>(deg, incl, boff, rowptr, cursor, NN);
    k_scatter<<<(EE + 255) / 256, 256, 0, stream>>>(ei, cursor, col);

    k_fragcnt<<<nb, 256, 0, stream>>>(fb, fcnt);
    int nbf = (FF + 255) / 256;
    k_scan1<<<nbf, 256, 0, stream>>>(fcnt, incl, bsum, FF);
    k_scan2<<<1, 1024, 0, stream>>>(bsum, boff, nbf);
    k_scan3<<<nbf, 256, 0, stream>>>(fcnt, incl, boff, fstart, (int*)nullptr, FF);

    for (int l = 0; l < NL; l++) {
        const float* ge1l = ge1 + (size_t)l * 6 * EMB;
        const float* ge2l = ge2 + (size_t)l * 3 * EMB;
        k_aggr<<<(NN + 3) / 4, 256, 0, stream>>>(h, ag, rowptr, col, cnt1, cnt2, ge1l, ge2l);
        for (int c0 = 0; c0 < NN; c0 += TCH) {
            int Mc = (NN - c0 < TCH) ? (NN - c0) : TCH;
            int mt1 = (Mc + 127) / 128;
            k_mfma<1><<<dim3(5, mt1), 256, 0, stream>>>(
                ag + (size_t)c0 * 320, nullptr,
                W1p + (size_t)l * 640 * 640, b1p + l * 640,
                th, tl, nullptr, 0);
            int mt2 = (Mc + 63) / 64;
            k_mfma<2><<<dim3(3, mt2), 256, 0, stream>>>(
                th, tl,
                W2p + (size_t)l * 384 * 1920, b2p + l * 384,
                nullptr, nullptr, h + (size_t)c0 * EMB, Mc);
        }
        hipMemsetAsync(colsum, 0, 2 * EMB * 4, stream);
        k_bnstats<<<nb, 256, 0, stream>>>(h, colsum, colsq);
        k_bnfinal<<<1, 320, 0, stream>>>(colsum, colsq, bng + (size_t)l * EMB, bnb + (size_t)l * EMB, scv);
        k_bnapply<<<(NN * EMB + 255) / 256, 256, 0, stream>>>(h, scv, (l < NL - 1) ? 1 : 0);
    }

    k_fragmean<<<(FF + 3) / 4, 256, 0, stream>>>(h, fstart, fragmean);
    k_build_out<<<(ND * HID + 255) / 256, 256, 0, stream>>>(h, fragmean, didx, fb, outb);
    k_out0<<<DD, 256, 0, stream>>>(outb, dei, dea, E1, E2, o0);
    k_logits<<<DD, 128, 0, stream>>>(o0, outb, dei, dout);
}

// Round 4
// 2214.927 us; speedup vs baseline: 6.7630x; 2.0206x over previous
//
#include <hip/hip_runtime.h>
#include <hip/hip_bf16.h>
#include <stdint.h>

#define NN 100000
#define EE 400000
#define ND 4096
#define DD 512
#define FF 8000
#define EMB 300
#define HID 600
#define NL 5
#define TCH 50176     // M-chunk rows (392*128), 2 chunks
#define MPAD 100096   // 782*128

typedef unsigned short u16;
typedef _Float16 f16x8 __attribute__((ext_vector_type(8)));
typedef float f32x4 __attribute__((ext_vector_type(4)));

static __device__ inline u16 f2h(float v) {
    union { _Float16 h; u16 u; } c; c.h = (_Float16)v; return c.u;
}
static __device__ inline float h2f(u16 u) {
    union { u16 u; _Float16 h; } c; c.u = u; return (float)c.h;
}
static __device__ inline uint32_t pk2(float a, float b) {
    return (uint32_t)f2h(a) | ((uint32_t)f2h(b) << 16);
}

// ---------------- node feature init (fp16, pad cols zeroed) ----------------
static __global__ void k_init_h(const int* __restrict__ x, const float* __restrict__ ae1,
                                const float* __restrict__ ae2, uint32_t* __restrict__ h) {
    int idx = blockIdx.x * 256 + threadIdx.x;
    if (idx >= NN * 160) return;
    int n = idx / 160, cw = idx - n * 160;
    int c = 2 * cw;
    int x0 = x[2 * n], x1 = x[2 * n + 1];
    float v0 = 0.f, v1 = 0.f;
    if (c < EMB)     v0 = ae1[x0 * EMB + c] + ae2[x1 * EMB + c];
    if (c + 1 < EMB) v1 = ae1[x0 * EMB + c + 1] + ae2[x1 * EMB + c + 1];
    h[idx] = pk2(v0, v1);
}

// ---------------- degree + edge-attr histograms ----------------
static __global__ void k_count(const int* __restrict__ ei, const int* __restrict__ ea,
                               int* __restrict__ deg, int* __restrict__ cnt1, int* __restrict__ cnt2) {
    int e = blockIdx.x * 256 + threadIdx.x;
    if (e >= EE) return;
    int dst = ei[EE + e];
    atomicAdd(&deg[dst], 1);
    atomicAdd(&cnt1[dst * 3 + ea[2 * e]], 1);
    atomicAdd(&cnt2[dst * 3 + ea[2 * e + 1]], 1);
}

// ---------------- generic 3-pass exclusive scan ----------------
static __global__ void k_scan1(const int* __restrict__ in, int* __restrict__ incl,
                               int* __restrict__ bsum, int L) {
    __shared__ int s[256];
    int t = threadIdx.x, i = blockIdx.x * 256 + t;
    int v = (i < L) ? in[i] : 0;
    s[t] = v; __syncthreads();
    for (int o = 1; o < 256; o <<= 1) {
        int xv = (t >= o) ? s[t - o] : 0; __syncthreads();
        s[t] += xv; __syncthreads();
    }
    if (i < L) incl[i] = s[t];
    if (t == 255) bsum[blockIdx.x] = s[255];
}

static __global__ void k_scan2(const int* __restrict__ bsum, int* __restrict__ boff, int nb) {
    __shared__ int s[1024];
    int t = threadIdx.x;
    int v = (t < nb) ? bsum[t] : 0;
    s[t] = v; __syncthreads();
    for (int o = 1; o < 1024; o <<= 1) {
        int xv = (t >= o) ? s[t - o] : 0; __syncthreads();
        s[t] += xv; __syncthreads();
    }
    if (t < nb) boff[t] = s[t] - v;
}

static __global__ void k_scan3(const int* __restrict__ in, const int* __restrict__ incl,
                               const int* __restrict__ boff, int* __restrict__ op,
                               int* __restrict__ cursor, int L) {
    int i = blockIdx.x * 256 + threadIdx.x;
    if (i >= L) return;
    int ex = incl[i] - in[i] + boff[i / 256];
    op[i] = ex;
    if (cursor) cursor[i] = ex;
    if (i == L - 1) op[L] = ex + in[i];
}

// ---------------- CSR scatter ----------------
static __global__ void k_scatter(const int* __restrict__ ei, int* __restrict__ cursor,
                                 int* __restrict__ col) {
    int e = blockIdx.x * 256 + threadIdx.x;
    if (e >= EE) return;
    int dst = ei[EE + e], src = ei[e];
    int p = atomicAdd(&cursor[dst], 1);
    col[p] = src;
}

// ---------------- GIN aggregation with fused BN-apply(+relu) of prev layer ----
// reads h fp16 (raw, pre-BN), applies v*sc[c]+sh[c] (and relu) on the fly.
static __global__ void k_aggr(const u16* __restrict__ h, u16* __restrict__ ag,
                              const int* __restrict__ rowptr, const int* __restrict__ col,
                              const int* __restrict__ cnt1, const int* __restrict__ cnt2,
                              const float* __restrict__ ge1l, const float* __restrict__ ge2l,
                              const float* __restrict__ scv, int relu) {
    __shared__ float se[7 * 320];
    for (int idx = threadIdx.x; idx < 7 * 320; idx += 256) {
        int g = idx / 320, c = idx - g * 320;
        float v = 0.f;
        if (c < EMB) {
            if (g < 3) v = ge1l[g * EMB + c];
            else if (g < 6) v = ge2l[(g - 3) * EMB + c];
            else v = ge1l[4 * EMB + c] + ge2l[c];
        }
        se[idx] = v;
    }
    __syncthreads();
    int wv = threadIdx.x >> 6, lane = threadIdx.x & 63;
    int n = blockIdx.x * 4 + wv;
    if (n >= NN) return;
    float c1a = (float)cnt1[n * 3], c1b = (float)cnt1[n * 3 + 1], c1c = (float)cnt1[n * 3 + 2];
    float c2a = (float)cnt2[n * 3], c2b = (float)cnt2[n * 3 + 1], c2c = (float)cnt2[n * 3 + 2];

    int cw[3];
    float sc0[3], sh0[3], sc1[3], sh1[3];
    float acc0[3], acc1[3];
    const uint32_t* hn = (const uint32_t*)(h + (size_t)n * 320);
#pragma unroll
    for (int j = 0; j < 3; j++) {
        cw[j] = lane + 64 * j;
        if (cw[j] < 160) {
            int c = 2 * cw[j];
            if (scv) { sc0[j] = scv[c]; sh0[j] = scv[320 + c]; sc1[j] = scv[c + 1]; sh1[j] = scv[321 + c]; }
            else     { sc0[j] = 1.f; sh0[j] = 0.f; sc1[j] = 1.f; sh1[j] = 0.f; }
            uint32_t hv = hn[cw[j]];
            float v0 = h2f(hv & 0xffff) * sc0[j] + sh0[j];
            float v1 = h2f(hv >> 16)    * sc1[j] + sh1[j];
            if (relu) { v0 = fmaxf(v0, 0.f); v1 = fmaxf(v1, 0.f); }
            acc0[j] = v0 + se[6 * 320 + c] + c1a * se[c] + c1b * se[320 + c] + c1c * se[640 + c]
                         + c2a * se[960 + c] + c2b * se[1280 + c] + c2c * se[1600 + c];
            acc1[j] = v1 + se[6 * 320 + c + 1] + c1a * se[c + 1] + c1b * se[321 + c] + c1c * se[641 + c]
                         + c2a * se[961 + c] + c2b * se[1281 + c] + c2c * se[1601 + c];
        }
    }
    int beg = rowptr[n], end = rowptr[n + 1];
    for (int p = beg; p < end; ++p) {
        const uint32_t* hr = (const uint32_t*)(h + (size_t)col[p] * 320);
#pragma unroll
        for (int j = 0; j < 3; j++) {
            if (cw[j] < 160) {
                uint32_t hv = hr[cw[j]];
                float v0 = h2f(hv & 0xffff) * sc0[j] + sh0[j];
                float v1 = h2f(hv >> 16)    * sc1[j] + sh1[j];
                if (relu) { v0 = fmaxf(v0, 0.f); v1 = fmaxf(v1, 0.f); }
                acc0[j] += v0; acc1[j] += v1;
            }
        }
    }
    uint32_t* ao = (uint32_t*)(ag + (size_t)n * 320);
#pragma unroll
    for (int j = 0; j < 3; j++)
        if (cw[j] < 160) ao[cw[j]] = pk2(acc0[j], acc1[j]);
}

// ---------------- weight packing: transposed, padded, fp16 ------------
// W1p [NL][640 n][320 k]
static __global__ void k_packW1(const float* __restrict__ W1, u16* __restrict__ W1p) {
    int idx = blockIdx.x * 256 + threadIdx.x;
    const int per = 640 * 320;
    if (idx >= NL * per) return;
    int l = idx / per, rem = idx % per;
    int n = rem / 320, k = rem % 320;
    float v = (k < EMB && n < HID) ? W1[(size_t)l * EMB * HID + (size_t)k * HID + n] : 0.f;
    W1p[idx] = f2h(v);
}

// W2p [NL][384 n][640 k]
static __global__ void k_packW2(const float* __restrict__ W2, u16* __restrict__ W2p) {
    int idx = blockIdx.x * 256 + threadIdx.x;
    const int per = 384 * 640;
    if (idx >= NL * per) return;
    int l = idx / per, rem = idx % per;
    int n = rem / 640, k = rem % 640;
    float v = (k < HID && n < EMB) ? W2[(size_t)l * HID * EMB + (size_t)k * EMB + n] : 0.f;
    W2p[idx] = f2h(v);
}

static __global__ void k_packb(const float* __restrict__ b1, const float* __restrict__ b2,
                               float* __restrict__ b1p, float* __restrict__ b2p) {
    int idx = blockIdx.x * 256 + threadIdx.x;
    if (idx < NL * 640) {
        int l = idx / 640, n = idx % 640;
        b1p[idx] = (n < HID) ? b1[l * HID + n] : 0.f;
    } else if (idx < NL * 640 + NL * 384) {
        int j = idx - NL * 640;
        int l = j / 384, n = j % 384;
        b2p[j] = (n < EMB) ? b2[l * EMB + n] : 0.f;
    }
}

// ---------------- MFMA GEMM (fp16) ------------------------------------
// MODE 1: t = relu(ag@W1p+b1) fp16.  BM=128, K=320, out stride 640.
// MODE 2: h = t@W2p+b2 fp16 + fused BN column stats. BM=64, K=640, out stride 320.
template <int MODE>
static __global__ __launch_bounds__(256) void k_mfma(
        const u16* __restrict__ A, const u16* __restrict__ B,
        const float* __restrict__ bias, u16* __restrict__ Out, int Mc,
        float* __restrict__ colsum, float* __restrict__ colsq) {
    constexpr int BM    = (MODE == 1) ? 128 : 64;
    constexpr int STR   = (MODE == 1) ? 320 : 640;
    constexpr int STRO  = (MODE == 1) ? 640 : 320;
    constexpr int NSTEP = (MODE == 1) ? 10 : 20;
    constexpr int MF = 4;
    constexpr int NF = (MODE == 1) ? 4 : 2;

    __shared__ __align__(16) u16 sA[BM * 32];
    __shared__ __align__(16) u16 sB[128 * 32];

    int tid = threadIdx.x;
    int lane = tid & 63, wv = tid >> 6;
    int wm = (MODE == 1) ? (wv >> 1) : 0;
    int wn = (MODE == 1) ? (wv & 1) : wv;
    int m0 = blockIdx.y * BM;
    int n0 = blockIdx.x * 128;
    int sr = tid >> 2, scb = tid & 3;

#define LOFF(row, cb) ((row) * 32 + (((cb) ^ (((row) >> 1) & 3)) * 8))
    uint4 rA0, rA1, rB0, rB1;
    auto do_load = [&](int ks) {
        int kk = ks * 32;
        const u16* as = A + (size_t)(m0 + sr) * STR + kk + scb * 8;
        rA0 = *(const uint4*)as;
        if (MODE == 1) rA1 = *(const uint4*)(as + (size_t)64 * STR);
        const u16* bs = B + (size_t)(n0 + sr) * STR + kk + scb * 8;
        rB0 = *(const uint4*)bs;
        rB1 = *(const uint4*)(bs + (size_t)64 * STR);
    };
    do_load(0);

    f32x4 acc[MF][NF];
#pragma unroll
    for (int i = 0; i < MF; i++)
#pragma unroll
        for (int j = 0; j < NF; j++) {
            acc[i][j][0] = 0.f; acc[i][j][1] = 0.f; acc[i][j][2] = 0.f; acc[i][j][3] = 0.f;
        }

    int lrow = lane & 15, lcb = lane >> 4;
    for (int ks = 0; ks < NSTEP; ++ks) {
        __syncthreads();
        *(uint4*)&sA[LOFF(sr, scb)] = rA0;
        if (MODE == 1) *(uint4*)&sA[LOFF(sr + 64, scb)] = rA1;
        *(uint4*)&sB[LOFF(sr, scb)] = rB0;
        *(uint4*)&sB[LOFF(sr + 64, scb)] = rB1;
        __syncthreads();
        if (ks + 1 < NSTEP) do_load(ks + 1);
        f16x8 af[MF], bfr[NF];
#pragma unroll
        for (int mf = 0; mf < MF; ++mf) {
            int r = wm * 64 + mf * 16 + lrow;
            af[mf] = *(const f16x8*)&sA[LOFF(r, lcb)];
        }
#pragma unroll
        for (int nf = 0; nf < NF; ++nf) {
            int r = wn * (NF * 16) + nf * 16 + lrow;
            bfr[nf] = *(const f16x8*)&sB[LOFF(r, lcb)];
        }
#pragma unroll
        for (int mf = 0; mf < MF; ++mf)
#pragma unroll
            for (int nf = 0; nf < NF; ++nf)
                acc[mf][nf] = __builtin_amdgcn_mfma_f32_16x16x32_f16(af[mf], bfr[nf], acc[mf][nf], 0, 0, 0);
    }
#undef LOFF

    int lrow4 = (lane >> 4) * 4, lcol = lane & 15;
    if (MODE == 1) {
#pragma unroll
        for (int mf = 0; mf < MF; ++mf)
#pragma unroll
            for (int nf = 0; nf < NF; ++nf) {
                int colg = n0 + wn * 64 + nf * 16 + lcol;
                float bv = bias[colg];
#pragma unroll
                for (int rg = 0; rg < 4; ++rg) {
                    int rowl = m0 + wm * 64 + mf * 16 + lrow4 + rg;
                    float v = fmaxf(acc[mf][nf][rg] + bv, 0.f);
                    Out[(size_t)rowl * STRO + colg] = f2h(v);
                }
            }
    } else {
#pragma unroll
        for (int nf = 0; nf < NF; ++nf) {
            int colg = n0 + wn * 32 + nf * 16 + lcol;
            float bv = bias[colg];
            float s = 0.f, q = 0.f;
#pragma unroll
            for (int mf = 0; mf < MF; ++mf)
#pragma unroll
                for (int rg = 0; rg < 4; ++rg) {
                    int rowl = m0 + mf * 16 + lrow4 + rg;
                    float v = acc[mf][nf][rg] + bv;
                    if (rowl < Mc) {
                        s += v; q += v * v;
                        if (colg < EMB) Out[(size_t)rowl * STRO + colg] = f2h(v);
                    }
                }
            s += __shfl_xor(s, 16); s += __shfl_xor(s, 32);
            q += __shfl_xor(q, 16); q += __shfl_xor(q, 32);
            if (lane < 16) { atomicAdd(&colsum[colg], s); atomicAdd(&colsq[colg], q); }
        }
    }
}

// ---------------- BN scale/shift from fused stats ----------------
static __global__ void k_bnfinal(const float* __restrict__ colsum, const float* __restrict__ colsq,
                                 const float* __restrict__ g, const float* __restrict__ b,
                                 float* __restrict__ scv) {
    int c = threadIdx.x;
    if (c >= EMB) return;
    float mean = colsum[c] * (1.f / NN);
    float var = colsq[c] * (1.f / NN) - mean * mean;
    float rs = rsqrtf(var + 1e-5f);
    float sc = rs * g[c];
    scv[c] = sc;
    scv[320 + c] = b[c] - mean * sc;
}

// final-layer BN apply (no relu), fp16 in-place
static __global__ void k_bnapply_final(uint32_t* __restrict__ h, const float* __restrict__ scv) {
    int idx = blockIdx.x * 256 + threadIdx.x;
    if (idx >= NN * 160) return;
    int cw = idx % 160, c = 2 * cw;
    uint32_t hv = h[idx];
    float v0 = h2f(hv & 0xffff) * scv[c] + scv[320 + c];
    float v1 = h2f(hv >> 16) * scv[c + 1] + scv[321 + c];
    h[idx] = pk2(v0, v1);
}

// ---------------- fragment pooling ----------------
static __global__ void k_fragcnt(const int* __restrict__ fb, int* __restrict__ fcnt) {
    int i = blockIdx.x * 256 + threadIdx.x;
    if (i >= NN) return;
    atomicAdd(&fcnt[fb[i]], 1);
}

static __global__ void k_fragmean(const u16* __restrict__ h, const int* __restrict__ fstart,
                                  float* __restrict__ fm) {
    int wv = threadIdx.x >> 6, lane = threadIdx.x & 63;
    int f = blockIdx.x * 4 + wv;
    if (f >= FF) return;
    int beg = fstart[f], end = fstart[f + 1];
    float inv = (end > beg) ? 1.f / (float)(end - beg) : 0.f;
    float a0[3], a1[3]; int cw[3];
#pragma unroll
    for (int j = 0; j < 3; j++) { cw[j] = lane + 64 * j; a0[j] = 0.f; a1[j] = 0.f; }
    for (int r = beg; r < end; ++r) {
        const uint32_t* hr = (const uint32_t*)(h + (size_t)r * 320);
#pragma unroll
        for (int j = 0; j < 3; j++)
            if (cw[j] < 160) {
                uint32_t hv = hr[cw[j]];
                a0[j] += h2f(hv & 0xffff); a1[j] += h2f(hv >> 16);
            }
    }
#pragma unroll
    for (int j = 0; j < 3; j++) {
        int c = 2 * cw[j];
        if (c < EMB)     fm[(size_t)f * EMB + c] = a0[j] * inv;
        if (c + 1 < EMB) fm[(size_t)f * EMB + c + 1] = a1[j] * inv;
    }
}

// ---------------- head ----------------
static __global__ void k_build_out(const u16* __restrict__ h, const float* __restrict__ fm,
                                   const int* __restrict__ didx, const int* __restrict__ fb,
                                   float* __restrict__ outb) {
    int idx = blockIdx.x * 256 + threadIdx.x;
    if (idx >= ND * HID) return;
    int d = idx / HID, c = idx - d * HID;
    int n = didx[d];
    float v = (c < EMB) ? h2f(h[(size_t)n * 320 + c]) : fm[(size_t)fb[n] * EMB + (c - EMB)];
    outb[idx] = v * (1.f / EMB);
}

// Mp[p] = fp16(E1[a] + E2[b]), p = a*3+b
static __global__ void k_precompM(const float* __restrict__ E1, const float* __restrict__ E2,
                                  u16* __restrict__ Mp) {
    int idx = blockIdx.x * 256 + threadIdx.x;
    const int per = HID * HID;
    if (idx >= 9 * per) return;
    int p = idx / per, i = idx % per;
    int a = p / 3, b = p % 3;
    Mp[idx] = f2h(E1[(size_t)a * per + i] + E2[(size_t)b * per + i]);
}

static __global__ void k_out0(const float* __restrict__ outb, const int* __restrict__ dei,
                              const int* __restrict__ dea, const u16* __restrict__ Mp,
                              float* __restrict__ o0) {
    __shared__ float v[HID];
    int d = blockIdx.x, tid = threadIdx.x;
    int r = dei[d];
    for (int c = tid; c < HID; c += 256) v[c] = outb[(size_t)r * HID + c];
    __syncthreads();
    int p = dea[2 * d] * 3 + dea[2 * d + 1];
    const u16* base = Mp + (size_t)p * HID * HID;
    float a0 = 0.f, a1 = 0.f, a2 = 0.f;
    for (int k = 0; k < HID; ++k) {
        float vk = v[k];
        const u16* row = base + (size_t)k * HID;
        a0 += vk * h2f(row[tid]);
        a1 += vk * h2f(row[tid + 256]);
        if (tid < 88) a2 += vk * h2f(row[tid + 512]);
    }
    o0[(size_t)d * HID + tid] = a0;
    o0[(size_t)d * HID + tid + 256] = a1;
    if (tid < 88) o0[(size_t)d * HID + tid + 512] = a2;
}

static __global__ void k_logits(const float* __restrict__ o0, const float* __restrict__ outb,
                                const int* __restrict__ dei, float* __restrict__ dout) {
    int d = blockIdx.x;
    int tid = threadIdx.x, lane = tid & 63;
    int which = tid >> 6;
    int dsel = which ? (d + DD - 1) % DD : d;
    const float* a = o0 + (size_t)d * HID;
    const float* bv = outb + (size_t)dei[DD + dsel] * HID;
    float s = 0.f;
    for (int c = lane; c < HID; c += 64) s += a[c] * bv[c];
    for (int o = 32; o > 0; o >>= 1) s += __shfl_down(s, o);
    if (lane == 0) dout[which ? DD + d : d] = s;
}

extern "C" void kernel_launch(void* const* d_in, const int* in_sizes, int n_in,
                              void* d_out, int out_size, void* d_ws, size_t ws_size,
                              hipStream_t stream) {
    const int* x    = (const int*)d_in[0];
    const int* ei   = (const int*)d_in[1];
    const int* ea   = (const int*)d_in[2];
    const int* didx = (const int*)d_in[3];
    const int* fb   = (const int*)d_in[4];
    const int* dei  = (const int*)d_in[5];
    const int* dea  = (const int*)d_in[6];
    const float* ae1 = (const float*)d_in[7];
    const float* ae2 = (const float*)d_in[8];
    const float* ge1 = (const float*)d_in[9];
    const float* ge2 = (const float*)d_in[10];
    const float* W1  = (const float*)d_in[11];
    const float* b1  = (const float*)d_in[12];
    const float* W2  = (const float*)d_in[13];
    const float* b2  = (const float*)d_in[14];
    const float* bng = (const float*)d_in[15];
    const float* bnb = (const float*)d_in[16];
    const float* E1  = (const float*)d_in[17];
    const float* E2  = (const float*)d_in[18];
    float* dout = (float*)d_out;

    char* w = (char*)d_ws;
    auto alloc = [&](size_t bytes) -> void* {
        void* p = (void*)w;
        w += (bytes + 255) & ~(size_t)255;
        return p;
    };
    u16* h   = (u16*)alloc((size_t)MPAD * 320 * 2);     // 64.1 MB
    u16* ag  = (u16*)alloc((size_t)MPAD * 320 * 2);     // 64.1 MB
    u16* t   = (u16*)alloc((size_t)TCH * 640 * 2);      // 64.2 MB
    u16* W1p = (u16*)alloc((size_t)NL * 640 * 320 * 2); //  2.1 MB
    u16* W2p = (u16*)alloc((size_t)NL * 384 * 640 * 2); //  2.5 MB
    u16* Mp  = (u16*)alloc((size_t)9 * HID * HID * 2);  //  6.5 MB
    float* b1p = (float*)alloc((size_t)NL * 640 * 4);
    float* b2p = (float*)alloc((size_t)NL * 384 * 4);
    int* rowptr = (int*)alloc((size_t)(NN + 1) * 4);
    int* cursor = (int*)alloc((size_t)NN * 4);
    int* col    = (int*)alloc((size_t)EE * 4);
    int* deg    = (int*)alloc((size_t)NN * 4);
    int* cnt1   = (int*)alloc((size_t)NN * 3 * 4);
    int* cnt2   = (int*)alloc((size_t)NN * 3 * 4);
    int* incl   = (int*)alloc((size_t)NN * 4);
    int* bsum   = (int*)alloc(4096);
    int* boff   = (int*)alloc(4096);
    int* fcnt   = (int*)alloc((size_t)FF * 4);
    int* fstart = (int*)alloc((size_t)(FF + 1) * 4);
    float* colsum = (float*)alloc(384 * 4);
    float* colsq  = (float*)alloc(384 * 4);
    float* scv    = (float*)alloc(640 * 4);
    // tail buffers overlay t (dead after last GEMM2): 20.7 MB < 64.2 MB
    float* fragmean = (float*)t;
    float* outb     = fragmean + (size_t)FF * EMB;
    float* o0       = outb + (size_t)ND * HID;
    // total ~ 209 MB

    hipMemsetAsync(deg, 0, (size_t)NN * 4, stream);
    hipMemsetAsync(cnt1, 0, (size_t)NN * 3 * 4, stream);
    hipMemsetAsync(cnt2, 0, (size_t)NN * 3 * 4, stream);
    hipMemsetAsync(fcnt, 0, (size_t)FF * 4, stream);

    k_packW1<<<(NL * 640 * 320 + 255) / 256, 256, 0, stream>>>(W1, W1p);
    k_packW2<<<(NL * 384 * 640 + 255) / 256, 256, 0, stream>>>(W2, W2p);
    k_packb<<<(NL * (640 + 384) + 255) / 256, 256, 0, stream>>>(b1, b2, b1p, b2p);
    k_precompM<<<(9 * HID * HID + 255) / 256, 256, 0, stream>>>(E1, E2, Mp);

    k_init_h<<<(NN * 160 + 255) / 256, 256, 0, stream>>>(x, ae1, ae2, (uint32_t*)h);
    k_count<<<(EE + 255) / 256, 256, 0, stream>>>(ei, ea, deg, cnt1, cnt2);

    int nb = (NN + 255) / 256;
    k_scan1<<<nb, 256, 0, stream>>>(deg, incl, bsum, NN);
    k_scan2<<<1, 1024, 0, stream>>>(bsum, boff, nb);
    k_scan3<<<nb, 256, 0, stream>>>(deg, incl, boff, rowptr, cursor, NN);
    k_scatter<<<(EE + 255) / 256, 256, 0, stream>>>(ei, cursor, col);

    k_fragcnt<<<nb, 256, 0, stream>>>(fb, fcnt);
    int nbf = (FF + 255) / 256;
    k_scan1<<<nbf, 256, 0, stream>>>(fcnt, incl, bsum, FF);
    k_scan2<<<1, 1024, 0, stream>>>(bsum, boff, nbf);
    k_scan3<<<nbf, 256, 0, stream>>>(fcnt, incl, boff, fstart, (int*)nullptr, FF);

    for (int l = 0; l < NL; l++) {
        const float* ge1l = ge1 + (size_t)l * 6 * EMB;
        const float* ge2l = ge2 + (size_t)l * 3 * EMB;
        // aggregation reads raw h of prev layer, applying prev BN (+relu) on the fly
        k_aggr<<<(NN + 3) / 4, 256, 0, stream>>>(h, ag, rowptr, col, cnt1, cnt2, ge1l, ge2l,
                                                 (l == 0) ? nullptr : scv, (l == 0) ? 0 : 1);
        hipMemsetAsync(colsum, 0, 384 * 4, stream);
        hipMemsetAsync(colsq, 0, 384 * 4, stream);
        for (int c0 = 0; c0 < NN; c0 += TCH) {
            int Mc = (NN - c0 < TCH) ? (NN - c0) : TCH;
            int mt1 = (Mc + 127) / 128;
            k_mfma<1><<<dim3(5, mt1), 256, 0, stream>>>(
                ag + (size_t)c0 * 320, W1p + (size_t)l * 640 * 320, b1p + l * 640,
                t, Mc, nullptr, nullptr);
            int mt2 = (Mc + 63) / 64;
            k_mfma<2><<<dim3(3, mt2), 256, 0, stream>>>(
                t, W2p + (size_t)l * 384 * 640, b2p + l * 384,
                h + (size_t)c0 * 320, Mc, colsum, colsq);
        }
        k_bnfinal<<<1, 320, 0, stream>>>(colsum, colsq, bng + (size_t)l * EMB, bnb + (size_t)l * EMB, scv);
    }
    // final layer: apply BN (no relu) to h in place
    k_bnapply_final<<<(NN * 160 + 255) / 256, 256, 0, stream>>>((uint32_t*)h, scv);

    k_fragmean<<<(FF + 3) / 4, 256, 0, stream>>>(h, fstart, fragmean);
    k_build_out<<<(ND * HID + 255) / 256, 256, 0, stream>>>(h, fragmean, didx, fb, outb);
    k_out0<<<DD, 256, 0, stream>>>(outb, dei, dea, Mp, o0);
    k_logits<<<DD, 128, 0, stream>>>(o0, outb, dei, dout);
}